// Round 1
// baseline (8938.831 us; speedup 1.0000x reference)
//
#include <hip/hip_runtime.h>
#include <hip/hip_cooperative_groups.h>

namespace cg = cooperative_groups;

typedef __attribute__((ext_vector_type(8))) short short8;
typedef __attribute__((ext_vector_type(4))) float floatx4;

#define T_STEPS 256
#define BATCH   64
#define IDIM    1024
#define HDIM    1024
#define KDIM    (IDIM + HDIM)   // fused [X | H] K dimension
#define MB      16              // batch rows per WG
#define HB      16              // hidden cols per WG (per gate)
#define NWG     256             // 4 batch-groups x 64 h-groups
#define NTHR    512             // 8 waves: (gate 0..3) x (k-half 0..1)
#define A_STRIDE (KDIM + 8)     // LDS row stride (+8 elems = 16B pad)

__device__ __forceinline__ unsigned short f2bf(float f) {
  unsigned u = __float_as_uint(f);
  u += 0x7FFFu + ((u >> 16) & 1u);   // round-to-nearest-even
  return (unsigned short)(u >> 16);
}

// Wcat[g][h][k] bf16, k<1024 -> Wx*mx, k>=1024 -> Wh*mh
__global__ void prep_weights(const float* __restrict__ Wx, const float* __restrict__ Wh,
                             const float* __restrict__ mx, const float* __restrict__ mh,
                             unsigned short* __restrict__ Wcat) {
  int idx = blockIdx.x * blockDim.x + threadIdx.x;   // over 4*1024*2048/4
  const int total = 4 * HDIM * KDIM / 4;
  if (idx >= total) return;
  int k4 = idx & (KDIM / 4 - 1);   // 0..511
  int gh = idx >> 9;               // g*1024 + h
  int k = k4 * 4;
  float4 v, m;
  if (k < IDIM) {
    v = *(const float4*)(Wx + (size_t)gh * IDIM + k);
    m = *(const float4*)(mx + (size_t)gh * IDIM + k);
  } else {
    v = *(const float4*)(Wh + (size_t)gh * HDIM + (k - IDIM));
    m = *(const float4*)(mh + (size_t)gh * HDIM + (k - IDIM));
  }
  ushort4 o;
  o.x = f2bf(v.x * m.x); o.y = f2bf(v.y * m.y);
  o.z = f2bf(v.z * m.z); o.w = f2bf(v.w * m.w);
  *(ushort4*)(Wcat + (size_t)gh * KDIM + k) = o;
}

__global__ void prep_h0(const float* __restrict__ H0, unsigned short* __restrict__ Hbuf0) {
  int i = blockIdx.x * blockDim.x + threadIdx.x;
  if (i < BATCH * HDIM) Hbuf0[i] = f2bf(H0[i]);
}

__global__ void __launch_bounds__(NTHR, 2)
lstm_main(const float* __restrict__ X,            // [T][B][I] f32
          const float* __restrict__ bias,          // [4][H] f32
          const float* __restrict__ C0,            // [B][H] f32
          const unsigned short* __restrict__ Wcat, // [4][H][K] bf16
          unsigned short* __restrict__ Hbuf0,      // [B][H] bf16 (double buffer)
          unsigned short* __restrict__ Hbuf1,
          float* __restrict__ out)                 // [T][B][H] f32
{
  cg::grid_group grid = cg::this_grid();

  __shared__ __align__(16) unsigned short Ash[MB * A_STRIDE];  // 65792 B
  __shared__ float parts[8][MB][HB + 1];                       // 8704 B

  const int tid  = threadIdx.x;
  const int wg   = blockIdx.x;
  const int bg   = wg >> 6;        // 0..3 batch group
  const int hg   = wg & 63;        // 0..63 hidden group
  const int b0   = bg * MB;
  const int h0   = hg * HB;

  const int wave = tid >> 6;       // 0..7
  const int lane = tid & 63;
  const int g    = wave & 3;       // gate
  const int kh   = wave >> 2;      // k half (0: X part, 1: H part)
  const int nl   = lane & 15;      // n for B-frag / m for A-frag
  const int quad = lane >> 4;

  // ---- persistent B fragments in VGPRs: B[n=lane&15][k = kh*1024 + ks*32 + quad*8 + j]
  short8 Bfr[32];
  {
    const short8* wp = (const short8*)Wcat;
    const int rowbase = (g * HDIM + h0 + nl) * (KDIM / 8);
    const int kbase   = kh * (IDIM / 8) + quad;
#pragma unroll
    for (int ks = 0; ks < 32; ++ks)
      Bfr[ks] = wp[rowbase + kbase + ks * 4];
  }

  // ---- per-thread cell state + bias (threads 0..255 own a (b,h) cell)
  float c_state = 0.f, bI = 0.f, bF = 0.f, bO = 0.f, bC = 0.f;
  const int eb = tid >> 4;   // batch row 0..15
  const int eh = tid & 15;   // h col 0..15
  if (tid < 256) {
    c_state = C0[(b0 + eb) * HDIM + h0 + eh];
    bI = bias[0 * HDIM + h0 + eh];
    bF = bias[1 * HDIM + h0 + eh];
    bO = bias[2 * HDIM + h0 + eh];
    bC = bias[3 * HDIM + h0 + eh];
  }

  for (int t = 0; t < T_STEPS; ++t) {
    const unsigned short* __restrict__ Hprev = (t & 1) ? Hbuf1 : Hbuf0;
    unsigned short* __restrict__ Hnext       = (t & 1) ? Hbuf0 : Hbuf1;

    // ---- stage A = [X_t slice | Hprev slice] into LDS (bf16)
    {
      const float4* xp = (const float4*)(X + ((size_t)t * BATCH + b0) * IDIM);
#pragma unroll
      for (int it = 0; it < (MB * IDIM / 4) / NTHR; ++it) {   // 8 iters
        int v = it * NTHR + tid;
        int m = v >> 8;
        int c4 = v & 255;
        float4 f = xp[m * (IDIM / 4) + c4];
        ushort4 o;
        o.x = f2bf(f.x); o.y = f2bf(f.y); o.z = f2bf(f.z); o.w = f2bf(f.w);
        *(ushort4*)&Ash[m * A_STRIDE + c4 * 4] = o;
      }
#pragma unroll
      for (int it = 0; it < (MB * HDIM / 8) / NTHR; ++it) {   // 4 iters
        int v = it * NTHR + tid;
        int m = v >> 7;
        int c8 = v & 127;
        uint4 d = *(const uint4*)(Hprev + (b0 + m) * HDIM + c8 * 8);
        *(uint4*)&Ash[m * A_STRIDE + IDIM + c8 * 8] = d;
      }
    }
    __syncthreads();

    // ---- MFMA: 16x16 tile, this wave's gate + k-half
    floatx4 acc = {0.f, 0.f, 0.f, 0.f};
    {
      const unsigned short* abase = &Ash[nl * A_STRIDE + kh * IDIM + quad * 8];
#pragma unroll
      for (int ks = 0; ks < 32; ++ks) {
        short8 af = *(const short8*)(abase + ks * 32);
        acc = __builtin_amdgcn_mfma_f32_16x16x32_bf16(af, Bfr[ks], acc, 0, 0, 0);
      }
    }
    // C/D layout: col = lane&15 (=n), row = quad*4 + reg (=m)
#pragma unroll
    for (int r = 0; r < 4; ++r)
      parts[wave][quad * 4 + r][nl] = acc[r];
    __syncthreads();

    // ---- elementwise LSTM cell update
    if (tid < 256) {
      float gI = parts[0][eb][eh] + parts[4][eb][eh] + bI;
      float gF = parts[1][eb][eh] + parts[5][eb][eh] + bF;
      float gO = parts[2][eb][eh] + parts[6][eb][eh] + bO;
      float gC = parts[3][eb][eh] + parts[7][eb][eh] + bC;
      float ig = 1.f / (1.f + __expf(-gI));
      float fg = 1.f / (1.f + __expf(-gF));
      float og = 1.f / (1.f + __expf(-gO));
      float cb = 1.f - 2.f / (__expf(2.f * gC) + 1.f);   // tanh, inf-safe
      c_state = fg * c_state + ig * cb;
      float hn = og * (1.f - 2.f / (__expf(2.f * c_state) + 1.f));
      out[((size_t)t * BATCH + b0 + eb) * HDIM + h0 + eh] = hn;
      Hnext[(b0 + eb) * HDIM + h0 + eh] = f2bf(hn);
    }
    grid.sync();
  }
}

extern "C" void kernel_launch(void* const* d_in, const int* in_sizes, int n_in,
                              void* d_out, int out_size, void* d_ws, size_t ws_size,
                              hipStream_t stream) {
  const float* X    = (const float*)d_in[0];
  const float* Wx   = (const float*)d_in[1];
  const float* Wh   = (const float*)d_in[2];
  const float* bias = (const float*)d_in[3];
  const float* mx   = (const float*)d_in[4];
  const float* mh   = (const float*)d_in[5];
  const float* H0   = (const float*)d_in[6];
  const float* C0   = (const float*)d_in[7];
  float* out = (float*)d_out;

  unsigned short* Wcat  = (unsigned short*)d_ws;                       // 16 MB
  unsigned short* Hbuf0 = Wcat + (size_t)4 * HDIM * KDIM;              // 128 KB
  unsigned short* Hbuf1 = Hbuf0 + BATCH * HDIM;                        // 128 KB

  {
    int tot = 4 * HDIM * KDIM / 4;
    prep_weights<<<(tot + 255) / 256, 256, 0, stream>>>(Wx, Wh, mx, mh, Wcat);
  }
  prep_h0<<<(BATCH * HDIM + 255) / 256, 256, 0, stream>>>(H0, Hbuf0);

  void* args[] = { (void*)&X, (void*)&bias, (void*)&C0, (void*)&Wcat,
                   (void*)&Hbuf0, (void*)&Hbuf1, (void*)&out };
  hipLaunchCooperativeKernel(reinterpret_cast<void*>(lstm_main),
                             dim3(NWG), dim3(NTHR), args, 0, stream);
}

// Round 2
// 6509.113 us; speedup vs baseline: 1.3733x; 1.3733x over previous
//
#include <hip/hip_runtime.h>

typedef __attribute__((ext_vector_type(8))) short short8;
typedef __attribute__((ext_vector_type(4))) float floatx4;

#define T_STEPS 256
#define BATCH   64
#define IDIM    1024
#define HDIM    1024
#define KDIM    (IDIM + HDIM)   // fused [X | H] K dimension
#define MB      16              // batch rows per WG
#define HB      16              // hidden cols per WG (per gate)
#define NWG     256             // 4 batch-groups x 64 h-groups
#define NTHR    512             // 8 waves = 8 K-octants (each does all 4 gates)
#define A_STRIDE (KDIM + 8)     // LDS row stride (+8 elems = 16B pad)
#define FLAG_STRIDE 16          // one flag per 64B

__device__ __forceinline__ unsigned short f2bf(float f) {
  unsigned u = __float_as_uint(f);
  u += 0x7FFFu + ((u >> 16) & 1u);   // round-to-nearest-even
  return (unsigned short)(u >> 16);
}

// Wcat[g][h][k] bf16, k<1024 -> Wx*mx, k>=1024 -> Wh*mh
__global__ void prep_weights(const float* __restrict__ Wx, const float* __restrict__ Wh,
                             const float* __restrict__ mx, const float* __restrict__ mh,
                             unsigned short* __restrict__ Wcat) {
  int idx = blockIdx.x * blockDim.x + threadIdx.x;
  const int total = 4 * HDIM * KDIM / 4;
  if (idx >= total) return;
  int k4 = idx & (KDIM / 4 - 1);
  int gh = idx >> 9;
  int k = k4 * 4;
  float4 v, m;
  if (k < IDIM) {
    v = *(const float4*)(Wx + (size_t)gh * IDIM + k);
    m = *(const float4*)(mx + (size_t)gh * IDIM + k);
  } else {
    v = *(const float4*)(Wh + (size_t)gh * HDIM + (k - IDIM));
    m = *(const float4*)(mh + (size_t)gh * HDIM + (k - IDIM));
  }
  ushort4 o;
  o.x = f2bf(v.x * m.x); o.y = f2bf(v.y * m.y);
  o.z = f2bf(v.z * m.z); o.w = f2bf(v.w * m.w);
  *(ushort4*)(Wcat + (size_t)gh * KDIM + k) = o;
}

__global__ void prep_h0(const float* __restrict__ H0, unsigned short* __restrict__ Hbuf0,
                        unsigned* __restrict__ flags) {
  int i = blockIdx.x * blockDim.x + threadIdx.x;
  if (i < BATCH * HDIM) Hbuf0[i] = f2bf(H0[i]);
  if (i < 4 * 64 * FLAG_STRIDE) flags[i] = 0u;
}

__global__ void __launch_bounds__(NTHR, 2)
lstm_main(const float* __restrict__ X,            // [T][B][I] f32
          const float* __restrict__ bias,          // [4][H] f32
          const float* __restrict__ C0,            // [B][H] f32
          const unsigned short* __restrict__ Wcat, // [4][H][K] bf16
          unsigned short* __restrict__ Hbuf0,      // [B][H] bf16 (double buffer)
          unsigned short* __restrict__ Hbuf1,
          unsigned* __restrict__ flags,            // [4][64*FLAG_STRIDE]
          float* __restrict__ out)                 // [T][B][H] f32
{
  __shared__ __align__(16) unsigned short Ash[MB * A_STRIDE];  // 65792 B
  __shared__ float parts[4][MB][HB + 1];                       // 4352 B

  const int tid  = threadIdx.x;
  const int wg   = blockIdx.x;
  const int bg   = wg >> 6;        // 0..3 batch group
  const int hg   = wg & 63;        // 0..63 hidden group
  const int b0   = bg * MB;
  const int h0   = hg * HB;

  const int w    = tid >> 6;       // wave = K-octant 0..7
  const int lane = tid & 63;
  const int nl   = lane & 15;      // n for B-frag / m for A-frag
  const int quad = lane >> 4;

  // ---- persistent B fragments: Bfr[g][ks] covers k = w*256 + ks*32 + quad*8 .. +8
  short8 Bfr[4][8];
  {
    const short8* wp = (const short8*)Wcat;
#pragma unroll
    for (int g = 0; g < 4; ++g) {
      const int rowbase = (g * HDIM + h0 + nl) * (KDIM / 8);
#pragma unroll
      for (int ks = 0; ks < 8; ++ks)
        Bfr[g][ks] = wp[rowbase + w * 32 + ks * 4 + quad];
    }
  }

  // ---- per-thread cell state (threads 0..255 own a (b,h) cell)
  float c_state = 0.f;
  const int eb = tid >> 4;   // batch row 0..15
  const int eh = tid & 15;   // h col 0..15
  if (tid < 256) c_state = C0[(b0 + eb) * HDIM + h0 + eh];

  // ---- bias pre-init values for the parts buffer (2 entries/thread)
  float* pflat = &parts[0][0][0];
  const int e0 = tid, e1 = tid + NTHR;        // over 4*16*16 gate-cell entries
  const int p0 = (e0 >> 8) * (MB * (HB + 1)) + ((e0 >> 4) & 15) * (HB + 1) + (e0 & 15);
  const int p1 = (e1 >> 8) * (MB * (HB + 1)) + ((e1 >> 4) & 15) * (HB + 1) + (e1 & 15);
  const float binit0 = bias[(e0 >> 8) * HDIM + h0 + (e0 & 15)];
  const float binit1 = bias[(e1 >> 8) * HDIM + h0 + (e1 & 15)];

  unsigned* myflag = flags + (bg * 64 + hg) * FLAG_STRIDE;
  unsigned* bgflags = flags + bg * 64 * FLAG_STRIDE;

  for (int t = 0; t < T_STEPS; ++t) {
    const unsigned short* __restrict__ Hprev = (t & 1) ? Hbuf1 : Hbuf0;
    unsigned short* __restrict__ Hnext       = (t & 1) ? Hbuf0 : Hbuf1;

    // ---- stage A = [X_t slice | Hprev slice] into LDS (bf16)
    {
      const float4* xp = (const float4*)(X + ((size_t)t * BATCH + b0) * IDIM);
#pragma unroll
      for (int it = 0; it < (MB * IDIM / 4) / NTHR; ++it) {   // 8 iters
        int v = it * NTHR + tid;
        int m = v >> 8;
        int c4 = v & 255;
        float4 f = xp[m * (IDIM / 4) + c4];
        ushort4 o;
        o.x = f2bf(f.x); o.y = f2bf(f.y); o.z = f2bf(f.z); o.w = f2bf(f.w);
        *(ushort4*)&Ash[m * A_STRIDE + c4 * 4] = o;
      }
#pragma unroll
      for (int it = 0; it < (MB * HDIM / 8) / NTHR; ++it) {   // 4 iters
        int v = it * NTHR + tid;
        int m = v >> 7;
        int c8 = v & 127;
        uint4 d = *(const uint4*)(Hprev + (b0 + m) * HDIM + c8 * 8);
        *(uint4*)&Ash[m * A_STRIDE + IDIM + c8 * 8] = d;
      }
    }
    // init parts with bias
    pflat[p0] = binit0;
    pflat[p1] = binit1;
    __syncthreads();

    // ---- MFMA: this wave's K-octant, all 4 gates (A-frag read once, used 4x)
    floatx4 acc[4];
#pragma unroll
    for (int g = 0; g < 4; ++g) acc[g] = floatx4{0.f, 0.f, 0.f, 0.f};
    {
      const unsigned short* abase = &Ash[nl * A_STRIDE + w * 256 + quad * 8];
#pragma unroll
      for (int ks = 0; ks < 8; ++ks) {
        short8 af = *(const short8*)(abase + ks * 32);
#pragma unroll
        for (int g = 0; g < 4; ++g)
          acc[g] = __builtin_amdgcn_mfma_f32_16x16x32_bf16(af, Bfr[g][ks], acc[g], 0, 0, 0);
      }
    }
    // cross-octant reduction: C/D layout col = lane&15 (=m... col=n), row = quad*4+reg
#pragma unroll
    for (int g = 0; g < 4; ++g)
#pragma unroll
      for (int r = 0; r < 4; ++r)
        atomicAdd(&parts[g][quad * 4 + r][nl], acc[g][r]);
    __syncthreads();

    // ---- elementwise LSTM cell update
    if (tid < 256) {
      float gI = parts[0][eb][eh];
      float gF = parts[1][eb][eh];
      float gO = parts[2][eb][eh];
      float gC = parts[3][eb][eh];
      float ig = 1.f / (1.f + __expf(-gI));
      float fg = 1.f / (1.f + __expf(-gF));
      float og = 1.f / (1.f + __expf(-gO));
      float cb = 1.f - 2.f / (__expf(2.f * gC) + 1.f);   // tanh, inf-safe
      c_state = fg * c_state + ig * cb;
      float hn = og * (1.f - 2.f / (__expf(2.f * c_state) + 1.f));
      out[((size_t)t * BATCH + b0 + eb) * HDIM + h0 + eh] = hn;
      Hnext[(b0 + eb) * HDIM + h0 + eh] = f2bf(hn);
    }
    // ---- per-batch-group barrier (replaces grid.sync)
    __syncthreads();   // drains vmcnt per wave -> Hnext stores are in L2
    if (tid == 0) {
      // release: writes back L2 so other XCDs can see Hnext, then publish
      __hip_atomic_store(myflag, (unsigned)(t + 1), __ATOMIC_RELEASE,
                         __HIP_MEMORY_SCOPE_AGENT);
    }
    if (tid < 64) {
      const unsigned target = (unsigned)(t + 1);
      while (__hip_atomic_load(&bgflags[tid * FLAG_STRIDE], __ATOMIC_RELAXED,
                               __HIP_MEMORY_SCOPE_AGENT) < target) {
        __builtin_amdgcn_s_sleep(1);
      }
      __threadfence();   // acquire: invalidate L1/L2 so Hprev reads are fresh
    }
    __syncthreads();
  }
}

extern "C" void kernel_launch(void* const* d_in, const int* in_sizes, int n_in,
                              void* d_out, int out_size, void* d_ws, size_t ws_size,
                              hipStream_t stream) {
  const float* X    = (const float*)d_in[0];
  const float* Wx   = (const float*)d_in[1];
  const float* Wh   = (const float*)d_in[2];
  const float* bias = (const float*)d_in[3];
  const float* mx   = (const float*)d_in[4];
  const float* mh   = (const float*)d_in[5];
  const float* H0   = (const float*)d_in[6];
  const float* C0   = (const float*)d_in[7];
  float* out = (float*)d_out;

  unsigned short* Wcat  = (unsigned short*)d_ws;                       // 16 MB
  unsigned short* Hbuf0 = Wcat + (size_t)4 * HDIM * KDIM;
  unsigned short* Hbuf1 = Hbuf0 + BATCH * HDIM;
  unsigned*       flags = (unsigned*)(Hbuf1 + BATCH * HDIM);           // 16 KB

  {
    int tot = 4 * HDIM * KDIM / 4;
    prep_weights<<<(tot + 255) / 256, 256, 0, stream>>>(Wx, Wh, mx, mh, Wcat);
  }
  prep_h0<<<(BATCH * HDIM + 255) / 256, 256, 0, stream>>>(H0, Hbuf0, flags);

  void* args[] = { (void*)&X, (void*)&bias, (void*)&C0, (void*)&Wcat,
                   (void*)&Hbuf0, (void*)&Hbuf1, (void*)&flags, (void*)&out };
  hipLaunchCooperativeKernel(reinterpret_cast<void*>(lstm_main),
                             dim3(NWG), dim3(NTHR), args, 0, stream);
}

// Round 3
// 3626.607 us; speedup vs baseline: 2.4648x; 1.7948x over previous
//
#include <hip/hip_runtime.h>

typedef __attribute__((ext_vector_type(8))) short short8;
typedef __attribute__((ext_vector_type(4))) float floatx4;

#define T_STEPS 256
#define BATCH   64
#define IDIM    1024
#define HDIM    1024
#define KDIM    (IDIM + HDIM)   // fused [X | H] K dimension
#define MB      16              // batch rows per WG
#define HB      16              // hidden cols per WG (per gate)
#define NWG     256             // 4 batch-groups x 64 h-groups
#define NTHR    512             // 8 waves = 8 K-octants (each does all 4 gates)
#define A_STRIDE (KDIM + 8)     // LDS row stride (+8 elems = 16B pad)
#define FLAG_STRIDE 16          // one flag per 64B

__device__ __forceinline__ unsigned short f2bf(float f) {
  unsigned u = __float_as_uint(f);
  u += 0x7FFFu + ((u >> 16) & 1u);   // round-to-nearest-even
  return (unsigned short)(u >> 16);
}

// Wcat[g][h][k] bf16, k<1024 -> Wx*mx, k>=1024 -> Wh*mh
__global__ void prep_weights(const float* __restrict__ Wx, const float* __restrict__ Wh,
                             const float* __restrict__ mx, const float* __restrict__ mh,
                             unsigned short* __restrict__ Wcat) {
  int idx = blockIdx.x * blockDim.x + threadIdx.x;
  const int total = 4 * HDIM * KDIM / 4;
  if (idx >= total) return;
  int k4 = idx & (KDIM / 4 - 1);
  int gh = idx >> 9;
  int k = k4 * 4;
  float4 v, m;
  if (k < IDIM) {
    v = *(const float4*)(Wx + (size_t)gh * IDIM + k);
    m = *(const float4*)(mx + (size_t)gh * IDIM + k);
  } else {
    v = *(const float4*)(Wh + (size_t)gh * HDIM + (k - IDIM));
    m = *(const float4*)(mh + (size_t)gh * HDIM + (k - IDIM));
  }
  ushort4 o;
  o.x = f2bf(v.x * m.x); o.y = f2bf(v.y * m.y);
  o.z = f2bf(v.z * m.z); o.w = f2bf(v.w * m.w);
  *(ushort4*)(Wcat + (size_t)gh * KDIM + k) = o;
}

__global__ void prep_h0(const float* __restrict__ H0, unsigned short* __restrict__ Hbuf0,
                        unsigned* __restrict__ flags) {
  int i = blockIdx.x * blockDim.x + threadIdx.x;
  if (i < BATCH * HDIM) Hbuf0[i] = f2bf(H0[i]);
  if (i < 4 * 64 * FLAG_STRIDE) flags[i] = 0u;
}

__global__ void __launch_bounds__(NTHR, 2)
lstm_main(const float* __restrict__ X,            // [T][B][I] f32
          const float* __restrict__ bias,          // [4][H] f32
          const float* __restrict__ C0,            // [B][H] f32
          const unsigned short* __restrict__ Wcat, // [4][H][K] bf16
          unsigned short* __restrict__ Hbuf0,      // [B][H] bf16 (double buffer)
          unsigned short* __restrict__ Hbuf1,
          unsigned* __restrict__ flags,            // [4][64*FLAG_STRIDE]
          float* __restrict__ out)                 // [T][B][H] f32
{
  __shared__ __align__(16) unsigned short Ash[MB * A_STRIDE];  // 65792 B
  __shared__ float parts[4][MB][HB + 1];                       // 4352 B

  const int tid  = threadIdx.x;
  const int wg   = blockIdx.x;
  const int bg   = wg >> 6;        // 0..3 batch group
  const int hg   = wg & 63;        // 0..63 hidden group
  const int b0   = bg * MB;
  const int h0   = hg * HB;

  const int w    = tid >> 6;       // wave = K-octant 0..7
  const int lane = tid & 63;
  const int nl   = lane & 15;      // n for B-frag / m for A-frag
  const int quad = lane >> 4;

  // ---- persistent B fragments: Bfr[g][ks] covers k = w*256 + ks*32 + quad*8 .. +8
  short8 Bfr[4][8];
  {
    const short8* wp = (const short8*)Wcat;
#pragma unroll
    for (int g = 0; g < 4; ++g) {
      const int rowbase = (g * HDIM + h0 + nl) * (KDIM / 8);
#pragma unroll
      for (int ks = 0; ks < 8; ++ks)
        Bfr[g][ks] = wp[rowbase + w * 32 + ks * 4 + quad];
    }
  }

  // ---- per-thread cell state (threads 0..255 own a (b,h) cell)
  float c_state = 0.f;
  const int eb = tid >> 4;   // batch row 0..15
  const int eh = tid & 15;   // h col 0..15
  if (tid < 256) c_state = C0[(b0 + eb) * HDIM + h0 + eh];

  // ---- bias pre-init values for the parts buffer (2 entries/thread)
  float* pflat = &parts[0][0][0];
  const int e0 = tid, e1 = tid + NTHR;        // over 4*16*16 gate-cell entries
  const int p0 = (e0 >> 8) * (MB * (HB + 1)) + ((e0 >> 4) & 15) * (HB + 1) + (e0 & 15);
  const int p1 = (e1 >> 8) * (MB * (HB + 1)) + ((e1 >> 4) & 15) * (HB + 1) + (e1 & 15);
  const float binit0 = bias[(e0 >> 8) * HDIM + h0 + (e0 & 15)];
  const float binit1 = bias[(e1 >> 8) * HDIM + h0 + (e1 & 15)];

  unsigned* myflag = flags + (bg * 64 + hg) * FLAG_STRIDE;
  // each thread's H-staging columns come from exactly one producer hg:
  const int c8 = tid & 127;                  // uint4 column index 0..127
  const int mrow = tid >> 7;                 // 0..3
  unsigned* depflag = flags + (bg * 64 + (c8 >> 1)) * FLAG_STRIDE;

  for (int t = 0; t < T_STEPS; ++t) {
    const unsigned short* __restrict__ Hprev = (t & 1) ? Hbuf1 : Hbuf0;
    unsigned short* __restrict__ Hnext       = (t & 1) ? Hbuf0 : Hbuf1;

    // ---- stage X slice into LDS (normal cached loads) + bias init (pre-poll)
    {
      const float4* xp = (const float4*)(X + ((size_t)t * BATCH + b0) * IDIM);
#pragma unroll
      for (int it = 0; it < (MB * IDIM / 4) / NTHR; ++it) {   // 8 iters
        int v = it * NTHR + tid;
        int m = v >> 8;
        int c4 = v & 255;
        float4 f = xp[m * (IDIM / 4) + c4];
        ushort4 o;
        o.x = f2bf(f.x); o.y = f2bf(f.y); o.z = f2bf(f.z); o.w = f2bf(f.w);
        *(ushort4*)&Ash[m * A_STRIDE + c4 * 4] = o;
      }
    }
    pflat[p0] = binit0;
    pflat[p1] = binit1;

    // ---- wait for this thread's H producer (device-coherent flag)
    {
      const unsigned tgt = (unsigned)t;
      while (__hip_atomic_load(depflag, __ATOMIC_RELAXED,
                               __HIP_MEMORY_SCOPE_AGENT) < tgt) {
        __builtin_amdgcn_s_sleep(1);
      }
    }

    // ---- stage H slice: coherence-point loads (bypass stale L1/L2), no buffer_inv
    {
      const unsigned short* pa = Hprev + (size_t)(b0 + mrow) * HDIM + c8 * 8;
      uint4 d0, d1, d2, d3;
      asm volatile(
        "global_load_dwordx4 %0, %4, off sc0 sc1\n\t"
        "global_load_dwordx4 %1, %5, off sc0 sc1\n\t"
        "global_load_dwordx4 %2, %6, off sc0 sc1\n\t"
        "global_load_dwordx4 %3, %7, off sc0 sc1\n\t"
        "s_waitcnt vmcnt(0)"
        : "=&v"(d0), "=&v"(d1), "=&v"(d2), "=&v"(d3)
        : "v"(pa), "v"(pa + 4 * HDIM), "v"(pa + 8 * HDIM), "v"(pa + 12 * HDIM)
        : "memory");
      *(uint4*)&Ash[(mrow +  0) * A_STRIDE + IDIM + c8 * 8] = d0;
      *(uint4*)&Ash[(mrow +  4) * A_STRIDE + IDIM + c8 * 8] = d1;
      *(uint4*)&Ash[(mrow +  8) * A_STRIDE + IDIM + c8 * 8] = d2;
      *(uint4*)&Ash[(mrow + 12) * A_STRIDE + IDIM + c8 * 8] = d3;
    }
    __syncthreads();

    // ---- MFMA: this wave's K-octant, all 4 gates (A-frag read once, used 4x)
    floatx4 acc[4];
#pragma unroll
    for (int g = 0; g < 4; ++g) acc[g] = floatx4{0.f, 0.f, 0.f, 0.f};
    {
      const unsigned short* abase = &Ash[nl * A_STRIDE + w * 256 + quad * 8];
#pragma unroll
      for (int ks = 0; ks < 8; ++ks) {
        short8 af = *(const short8*)(abase + ks * 32);
#pragma unroll
        for (int g = 0; g < 4; ++g)
          acc[g] = __builtin_amdgcn_mfma_f32_16x16x32_bf16(af, Bfr[g][ks], acc[g], 0, 0, 0);
      }
    }
    // cross-octant reduction: C/D layout col = lane&15, row = quad*4+reg
#pragma unroll
    for (int g = 0; g < 4; ++g)
#pragma unroll
      for (int r = 0; r < 4; ++r)
        atomicAdd(&parts[g][quad * 4 + r][nl], acc[g][r]);
    __syncthreads();

    // ---- elementwise LSTM cell update + coherent H store
    if (tid < 256) {
      float gI = parts[0][eb][eh];
      float gF = parts[1][eb][eh];
      float gO = parts[2][eb][eh];
      float gC = parts[3][eb][eh];
      float ig = 1.f / (1.f + __expf(-gI));
      float fg = 1.f / (1.f + __expf(-gF));
      float og = 1.f / (1.f + __expf(-gO));
      float cb = 1.f - 2.f / (__expf(2.f * gC) + 1.f);   // tanh, inf-safe
      c_state = fg * c_state + ig * cb;
      float hn = og * (1.f - 2.f / (__expf(2.f * c_state) + 1.f));
      out[((size_t)t * BATCH + b0 + eb) * HDIM + h0 + eh] = hn;
      unsigned short hb = f2bf(hn);
      unsigned short* ps = Hnext + (size_t)(b0 + eb) * HDIM + h0 + eh;
      asm volatile("global_store_short %0, %1, off sc0 sc1"
                   :: "v"(ps), "v"((unsigned)hb) : "memory");
    }
    // all H stores of this wave acked at coherence point before flag publish
    asm volatile("s_waitcnt vmcnt(0)" ::: "memory");
    __syncthreads();   // all waves' H stores done
    if (tid == 0) {
      __hip_atomic_store(myflag, (unsigned)(t + 1), __ATOMIC_RELAXED,
                         __HIP_MEMORY_SCOPE_AGENT);
    }
  }
}

extern "C" void kernel_launch(void* const* d_in, const int* in_sizes, int n_in,
                              void* d_out, int out_size, void* d_ws, size_t ws_size,
                              hipStream_t stream) {
  const float* X    = (const float*)d_in[0];
  const float* Wx   = (const float*)d_in[1];
  const float* Wh   = (const float*)d_in[2];
  const float* bias = (const float*)d_in[3];
  const float* mx   = (const float*)d_in[4];
  const float* mh   = (const float*)d_in[5];
  const float* H0   = (const float*)d_in[6];
  const float* C0   = (const float*)d_in[7];
  float* out = (float*)d_out;

  unsigned short* Wcat  = (unsigned short*)d_ws;                       // 16 MB
  unsigned short* Hbuf0 = Wcat + (size_t)4 * HDIM * KDIM;
  unsigned short* Hbuf1 = Hbuf0 + BATCH * HDIM;
  unsigned*       flags = (unsigned*)(Hbuf1 + BATCH * HDIM);           // 16 KB

  {
    int tot = 4 * HDIM * KDIM / 4;
    prep_weights<<<(tot + 255) / 256, 256, 0, stream>>>(Wx, Wh, mx, mh, Wcat);
  }
  prep_h0<<<(BATCH * HDIM + 255) / 256, 256, 0, stream>>>(H0, Hbuf0, flags);

  void* args[] = { (void*)&X, (void*)&bias, (void*)&C0, (void*)&Wcat,
                   (void*)&Hbuf0, (void*)&Hbuf1, (void*)&flags, (void*)&out };
  hipLaunchCooperativeKernel(reinterpret_cast<void*>(lstm_main),
                             dim3(NWG), dim3(NTHR), args, 0, stream);
}